// Round 1
// baseline (409.466 us; speedup 1.0000x reference)
//
#include <hip/hip_runtime.h>

#define NN 4096
#define DIN 64
#define DOUTC 16
#define CCH 4
#define K_TOT (NN*CCH)        // 16384
#define N_OUT (DOUTC*CCH)     // 64

typedef __bf16 bf16x8 __attribute__((ext_vector_type(8)));
typedef __bf16 bf16x4 __attribute__((ext_vector_type(4)));
typedef float  f32x4  __attribute__((ext_vector_type(4)));

// ---------------- kernel 0: out = bias ----------------
__global__ void bias_init_kernel(const float* __restrict__ bias,
                                 float* __restrict__ out) {
    int t = blockIdx.x * blockDim.x + threadIdx.x;
    ((f32x4*)out)[t] = ((const f32x4*)bias)[t];
}

// ---------------- kernel 1: build Bt [64][16384] bf16 ----------------
// Bt[(r*4+c)][(j*4+cp)] = S[j][r][(c-cp)&3]
// where S[j][r][cc] = sum_d sum_cp feat[j][d][cp] * w[d][r][(cc-cp)&3]
__global__ void support_kernel(const float* __restrict__ feat,  // [4096][64][4]
                               const float* __restrict__ wgt,   // [64][16][4]
                               __bf16* __restrict__ Bt) {
    const int t  = threadIdx.x;
    const int r  = t & 15;
    const int jl = t >> 4;                 // 0..15
    const int j  = blockIdx.x * 16 + jl;

    float a0 = 0.f, a1 = 0.f, a2 = 0.f, a3 = 0.f;
    const f32x4* f4 = (const f32x4*)(feat + (size_t)j * DIN * CCH);
    const f32x4* w4 = (const f32x4*)wgt;
    #pragma unroll 8
    for (int d = 0; d < DIN; ++d) {
        f32x4 f = f4[d];
        f32x4 w = w4[d * 16 + r];
        a0 += f[0]*w[0] + f[1]*w[3] + f[2]*w[2] + f[3]*w[1];
        a1 += f[0]*w[1] + f[1]*w[0] + f[2]*w[3] + f[3]*w[2];
        a2 += f[0]*w[2] + f[1]*w[1] + f[2]*w[0] + f[3]*w[3];
        a3 += f[0]*w[3] + f[1]*w[2] + f[2]*w[1] + f[3]*w[0];
    }
    float accs[4] = {a0, a1, a2, a3};
    #pragma unroll
    for (int cc = 0; cc < 4; ++cc) {
        #pragma unroll
        for (int cp = 0; cp < 4; ++cp) {
            int n = r * 4 + ((cc + cp) & 3);
            Bt[(size_t)n * K_TOT + j * 4 + cp] = (__bf16)accs[cc];
        }
    }
}

// ---------------- kernel 2: out += adj[4096][16384] x Bt^T ----------------
#define BM 64
#define BK 128
#define KCHUNKS 8      // per-block K range = 8*128 = 1024
#define KSPLIT 16      // grid.y

__launch_bounds__(256, 4)
__global__ void gemm_kernel(const float* __restrict__ A,    // adj, [4096][16384] f32
                            const __bf16* __restrict__ Bt,  // [64][16384] bf16
                            float* __restrict__ out) {      // [4096][64] f32
    __shared__ __align__(16) __bf16 lA[BM * BK];     // XOR-swizzled
    __shared__ __align__(16) __bf16 lB[N_OUT * BK];  // XOR-swizzled

    const int t    = threadIdx.x;
    const int wave = t >> 6;
    const int lane = t & 63;
    const int i0   = blockIdx.x * BM;
    const int kbase = blockIdx.y * (KCHUNKS * BK);

    char* lAc = (char*)lA;
    char* lBc = (char*)lB;

    f32x4 acc[4] = {};

    const int mrow = wave * 16 + (lane & 15);
    const int kgrp = lane >> 4;    // 0..3

    for (int c = 0; c < KCHUNKS; ++c) {
        const int k0 = kbase + c * BK;
        // stage A tile 64x128 f32 -> bf16 LDS (swizzled)
        #pragma unroll
        for (int it = 0; it < 8; ++it) {
            int idx = it * 256 + t;          // 0..2047
            int m   = idx >> 5;              // 0..63
            int c4  = idx & 31;              // float4 col
            f32x4 v = *(const f32x4*)(A + (size_t)(i0 + m) * K_TOT + k0 + c4 * 4);
            bf16x4 b;
            b[0] = (__bf16)v[0]; b[1] = (__bf16)v[1];
            b[2] = (__bf16)v[2]; b[3] = (__bf16)v[3];
            int byte = (m * 256 + c4 * 8) ^ ((m & 7) << 4);
            *(bf16x4*)(lAc + byte) = b;
        }
        // stage B tile 64x128 bf16 (swizzled)
        #pragma unroll
        for (int it = 0; it < 4; ++it) {
            int idx = it * 256 + t;          // 0..1023
            int n   = idx >> 4;              // 0..63
            int c8  = idx & 15;              // 16B col
            uint4 v = *(const uint4*)(Bt + (size_t)n * K_TOT + k0 + c8 * 8);
            int byte = (n * 256 + c8 * 16) ^ ((n & 7) << 4);
            *(uint4*)(lBc + byte) = v;
        }
        __syncthreads();

        #pragma unroll
        for (int kk = 0; kk < 4; ++kk) {
            int abyte = (mrow * 256 + kk * 64 + kgrp * 16) ^ ((mrow & 7) << 4);
            bf16x8 af = *(const bf16x8*)(lAc + abyte);
            #pragma unroll
            for (int nf = 0; nf < 4; ++nf) {
                int n = nf * 16 + (lane & 15);
                int bbyte = (n * 256 + kk * 64 + kgrp * 16) ^ ((n & 7) << 4);
                bf16x8 bf = *(const bf16x8*)(lBc + bbyte);
                acc[nf] = __builtin_amdgcn_mfma_f32_16x16x32_bf16(af, bf, acc[nf], 0, 0, 0);
            }
        }
        __syncthreads();
    }

    // epilogue: atomicAdd partials (KSPLIT blocks contribute per output)
    const int col  = lane & 15;
    const int rowg = lane >> 4;
    #pragma unroll
    for (int nf = 0; nf < 4; ++nf) {
        #pragma unroll
        for (int e = 0; e < 4; ++e) {
            int i = i0 + wave * 16 + rowg * 4 + e;
            int n = nf * 16 + col;
            atomicAdd(&out[(size_t)i * N_OUT + n], acc[nf][e]);
        }
    }
}

extern "C" void kernel_launch(void* const* d_in, const int* in_sizes, int n_in,
                              void* d_out, int out_size, void* d_ws, size_t ws_size,
                              hipStream_t stream) {
    const float* feat = (const float*)d_in[0];  // [4096][64][4]
    const float* adj  = (const float*)d_in[1];  // [4096][4096][4]
    const float* wgt  = (const float*)d_in[2];  // [64][16][4]
    const float* bias = (const float*)d_in[3];  // [4096][16][4]
    float* out = (float*)d_out;                 // [4096][16][4]
    __bf16* Bt = (__bf16*)d_ws;                 // [64][16384] bf16, 2 MB

    // out = bias  (262144 floats = 65536 float4)
    bias_init_kernel<<<256, 256, 0, stream>>>(bias, out);
    // build Bt
    support_kernel<<<NN / 16, 256, 0, stream>>>(feat, wgt, Bt);
    // out += adj x Bt^T
    dim3 grid(NN / BM, KSPLIT);
    gemm_kernel<<<grid, 256, 0, stream>>>(adj, Bt, out);
}